// Round 15
// baseline (508.807 us; speedup 1.0000x reference)
//
#include <hip/hip_runtime.h>
#include <hip/hip_bf16.h>

#define B_ 128
#define T_ 512
#define C_ 1024

typedef __attribute__((ext_vector_type(8))) short short8;
typedef __attribute__((ext_vector_type(4))) float f32x4;

__device__ __forceinline__ unsigned short f2bf(float f){
  unsigned u; __builtin_memcpy(&u, &f, 4);
  u += 0x7FFFu + ((u >> 16) & 1u);          // RNE
  return (unsigned short)(u >> 16);
}

// ---- async global->LDS 16B (LDS dest: wave-uniform base + lane*16)
typedef __attribute__((address_space(3))) unsigned lds_u32_t;
typedef __attribute__((address_space(1))) unsigned glb_u32_t;
typedef __attribute__((address_space(3))) char lds_char;
__device__ __forceinline__ void gload16(const void* g, void* l){
  __builtin_amdgcn_global_load_lds((const glb_u32_t*)g, (lds_u32_t*)l, 16, 0, 0);
}

// ---------------- cast f32 -> bf16 (vectorized; weights only) ----------------
__global__ void cast_f32_bf16(const float* __restrict__ in, unsigned short* __restrict__ out, long n){
  long i = (long)blockIdx.x * blockDim.x + threadIdx.x;
  long stride = (long)gridDim.x * blockDim.x;
  for (long j = i * 4; j < n; j += stride * 4){
    float4 v = *(const float4*)(in + j);
    ushort4 o; o.x = f2bf(v.x); o.y = f2bf(v.y); o.z = f2bf(v.z); o.w = f2bf(v.w);
    *(ushort4*)(out + j) = o;
  }
}

// ---------------- transpose-cast W_proj (e,c) -> WpT (c,e) bf16 ----------------
__global__ void transpose_cast(const float* __restrict__ in, unsigned short* __restrict__ out){
  __shared__ float tile[32][33];
  int c0 = blockIdx.x * 32, e0 = blockIdx.y * 32;
  int tx = threadIdx.x, ty = threadIdx.y;     // (32,8)
  for (int r = 0; r < 32; r += 8)
    tile[ty + r][tx] = in[(size_t)(e0 + ty + r) * C_ + c0 + tx];
  __syncthreads();
  for (int r = 0; r < 32; r += 8)
    out[(size_t)(c0 + ty + r) * C_ + e0 + tx] = f2bf(tile[tx][ty + r]);
}

// ---------------- small bf16 GEMM (weight fuse), m97-style 128x128 ----------------
__global__ __launch_bounds__(256) void gemm_bt_bf16(
    const unsigned short* __restrict__ A,   // M x K
    const unsigned short* __restrict__ Bt,  // N x K
    unsigned short* __restrict__ Cc,        // M x N
    int M, int N, int K)
{
  __shared__ short As[128 * 32];
  __shared__ short Bs[128 * 32];
  const int tid  = threadIdx.x;
  const int lane = tid & 63;
  const int wave = tid >> 6;
  const int wr = wave >> 1, wc = wave & 1;
  const int lr = lane & 15, kg = lane >> 4;
  const int m0 = blockIdx.x * 128;
  const int n0 = blockIdx.y * 128;

  f32x4 acc[4][4];
  #pragma unroll
  for (int mi = 0; mi < 4; mi++)
    #pragma unroll
    for (int ni = 0; ni < 4; ni++)
      acc[mi][ni] = (f32x4){0.f, 0.f, 0.f, 0.f};

  const int r1 = tid >> 2, ch1 = tid & 3;
  char* abase = (char*)As + (tid & ~63) * 16;
  char* bbase = (char*)Bs + (tid & ~63) * 16;

  for (int k0 = 0; k0 < K; k0 += 32){
    __syncthreads();
    gload16(A  + (size_t)(m0 + r1)      * K + k0 + ch1 * 8, abase);
    gload16(A  + (size_t)(m0 + 64 + r1) * K + k0 + ch1 * 8, abase + 4096);
    gload16(Bt + (size_t)(n0 + r1)      * K + k0 + ch1 * 8, bbase);
    gload16(Bt + (size_t)(n0 + 64 + r1) * K + k0 + ch1 * 8, bbase + 4096);
    __syncthreads();

    short8 af[4], bfr[4];
    #pragma unroll
    for (int mi = 0; mi < 4; mi++)
      af[mi] = *(const short8*)&As[(wr * 64 + mi * 16 + lr) * 32 + kg * 8];
    #pragma unroll
    for (int ni = 0; ni < 4; ni++)
      bfr[ni] = *(const short8*)&Bs[(wc * 64 + ni * 16 + lr) * 32 + kg * 8];
    #pragma unroll
    for (int mi = 0; mi < 4; mi++)
      #pragma unroll
      for (int ni = 0; ni < 4; ni++)
        acc[mi][ni] = __builtin_amdgcn_mfma_f32_16x16x32_bf16(af[mi], bfr[ni], acc[mi][ni], 0, 0, 0);
  }

  #pragma unroll
  for (int mi = 0; mi < 4; mi++)
    #pragma unroll
    for (int ni = 0; ni < 4; ni++){
      int n = n0 + wc * 64 + ni * 16 + lr;
      int mb = m0 + wr * 64 + mi * 16 + kg * 4;
      #pragma unroll
      for (int j = 0; j < 4; j++)
        Cc[(size_t)(mb + j) * N + n] = f2bf(acc[mi][ni][j]);
    }
}

// ======= 256x256 GEMM, FUSED f32->bf16 A-staging + lgkm LADDER (r12 base, 247us) =======
// Reads issued bfr-first then af; waits laddered lgkmcnt(7..0) so remaining ds_reads
// retire UNDER MFMA issue (DS ops retire in-order per wave; r12's lgkm(12) split relied
// on the same property). Everything else r12-exact.
#define SWZ(x) ((x) ^ ((((x) >> 7) & 3) << 4))

#define STAGE_B(kt, kh) { \
  int d_ = wv * 1024 + ln * 16; int o_ = SWZ(d_); \
  gload16(Bg + (size_t)(n0 + (o_ >> 6)) * 1024 + (kt) * 64 + (kh) * 32 + ((o_ >> 4) & 3) * 8, \
          ldsc + 65536 + ((kt) & 1) * 32768 + (kh) * 16384 + wv * 1024); \
  d_ += 8192; o_ = SWZ(d_); \
  gload16(Bg + (size_t)(n0 + (o_ >> 6)) * 1024 + (kt) * 64 + (kh) * 32 + ((o_ >> 4) & 3) * 8, \
          ldsc + 65536 + ((kt) & 1) * 32768 + (kh) * 16384 + 8192 + wv * 1024); }

#define LOADA(kt) { \
  _Pragma("unroll") for (int kh = 0; kh < 2; kh++) \
    _Pragma("unroll") for (int hf = 0; hf < 2; hf++){ \
      const float* p_ = Ag32 + (size_t)(m0 + rowA + hf * 128) * 1024 + (kt) * 64 + kh * 32 + c8 * 8; \
      areg[kh][hf][0] = *(const float4*)p_; \
      areg[kh][hf][1] = *(const float4*)(p_ + 4); } }

#define CVTWRITE(slot) { \
  _Pragma("unroll") for (int kh = 0; kh < 2; kh++) \
    _Pragma("unroll") for (int hf = 0; hf < 2; hf++){ \
      short8 w_; \
      _Pragma("unroll") for (int q = 0; q < 4; q++){ \
        w_[q]     = (short)f2bf(areg[kh][hf][0][q]); \
        w_[q + 4] = (short)f2bf(areg[kh][hf][1][q]); } \
      int d_ = wv * 1024 + ln * 16 + hf * 8192; \
      unsigned ad_ = (unsigned)(size_t)(lds3 + (slot) * 32768 + kh * 16384 + SWZ(d_)); \
      asm volatile("ds_write_b128 %0, %1" :: "v"(ad_), "v"(w_)); } }

#define MFMA4(MI) { \
  acc[MI][0] = __builtin_amdgcn_mfma_f32_16x16x32_bf16(af[MI], bfr[0], acc[MI][0], 0, 0, 0); \
  acc[MI][1] = __builtin_amdgcn_mfma_f32_16x16x32_bf16(af[MI], bfr[1], acc[MI][1], 0, 0, 0); \
  acc[MI][2] = __builtin_amdgcn_mfma_f32_16x16x32_bf16(af[MI], bfr[2], acc[MI][2], 0, 0, 0); \
  acc[MI][3] = __builtin_amdgcn_mfma_f32_16x16x32_bf16(af[MI], bfr[3], acc[MI][3], 0, 0, 0); }

#define LSTEP(N, MI) { \
  asm volatile("s_waitcnt lgkmcnt(" #N ")"); \
  __builtin_amdgcn_sched_barrier(0); \
  MFMA4(MI); }

// one K-half: issue 4 bfr + 8 af reads, then laddered wait/MFMA
#define KHALF(S, KHOFF) { \
  _Pragma("unroll") for (int ni = 0; ni < 4; ni++){ \
    int off = 65536 + (S) * 32768 + (KHOFF) + (wc * 64 + ni * 16 + lr) * 64 + kg * 16; \
    unsigned a_ = (unsigned)(size_t)(lds3 + SWZ(off)); \
    asm volatile("ds_read_b128 %0, %1" : "=v"(bfr[ni]) : "v"(a_)); } \
  _Pragma("unroll") for (int mi = 0; mi < 8; mi++){ \
    int off = (S) * 32768 + (KHOFF) + (wr * 128 + mi * 16 + lr) * 64 + kg * 16; \
    unsigned a_ = (unsigned)(size_t)(lds3 + SWZ(off)); \
    asm volatile("ds_read_b128 %0, %1" : "=v"(af[mi]) : "v"(a_)); } \
  __builtin_amdgcn_s_setprio(1); \
  LSTEP(7, 0) LSTEP(6, 1) LSTEP(5, 2) LSTEP(4, 3) \
  LSTEP(3, 4) LSTEP(2, 5) LSTEP(1, 6) LSTEP(0, 7) \
  __builtin_amdgcn_s_setprio(0); \
  __builtin_amdgcn_sched_barrier(0); }

__global__ __launch_bounds__(512, 2) void gemm256_fused(
    const float* __restrict__ Ag32,         // 65536 x 1024 f32 (x)
    const unsigned short* __restrict__ Bg,  // 1024 x 1024 bf16 (W_f)
    unsigned short* __restrict__ vt)        // (C, B, T)
{
  extern __shared__ char ldsc[];            // 131072 B
  lds_char* lds3 = (lds_char*)ldsc;
  const int tid = threadIdx.x;
  const int ln  = tid & 63;
  const int wv  = tid >> 6;                 // 8 waves
  const int wr  = wv >> 2;                  // 2 M-waves (128 rows each)
  const int wc  = wv & 3;                   // 4 N-waves (64 cols each)
  const int lr  = ln & 15, kg = ln >> 4;
  const int rowA = wv * 16 + (ln >> 2);     // A staging row (0..127), +128 for hf=1
  const int c8   = ln & 3;                  // A staging 8-f32 chunk within 32-col k-half
  // bijective XCD chunk: 4 n-tiles of each A-panel consecutive per XCD.
  const int id  = blockIdx.x;
  const int jj  = (id & 7) * 128 + (id >> 3);
  const int n0  = (jj & 3) * 256;
  const int m0  = (jj >> 2) * 256;

  f32x4 acc[8][4];
  #pragma unroll
  for (int mi = 0; mi < 8; mi++)
    #pragma unroll
    for (int ni = 0; ni < 4; ni++)
      acc[mi][ni] = (f32x4){0.f, 0.f, 0.f, 0.f};

  float4 areg[2][2][2];

  // prologue: tile0 -> slot0 (A via load+cvt+write, B via gload16)
  LOADA(0);
  asm volatile("s_waitcnt vmcnt(0)");
  __builtin_amdgcn_sched_barrier(0);
  CVTWRITE(0);
  __builtin_amdgcn_sched_barrier(0);
  STAGE_B(0, 0); STAGE_B(0, 1);
  __builtin_amdgcn_sched_barrier(0);
  asm volatile("s_waitcnt lgkmcnt(0)");     // A writes retired
  __builtin_amdgcn_sched_barrier(0);
  asm volatile("s_waitcnt vmcnt(0)");       // B(0) landed
  __builtin_amdgcn_sched_barrier(0);
  __builtin_amdgcn_s_barrier();

  short8 af[8], bfr[4];                     // single-buffered fragments

  #pragma unroll 1
  for (int t = 0; t < 16; ++t){
    const int S = t & 1;

    // issue next tile's A reg-loads + B DMAs early; consumed at iter bottom
    if (t < 15){
      LOADA(t + 1);
      __builtin_amdgcn_sched_barrier(0);
      STAGE_B(t + 1, 0); STAGE_B(t + 1, 1);
      __builtin_amdgcn_sched_barrier(0);
    }

    KHALF(S, 0)         // K-half 0: reads + laddered MFMA
    KHALF(S, 16384)     // K-half 1

    // ---- bottom: consume A(t+1) regs, write slot S^1
    if (t < 15){
      asm volatile("s_waitcnt vmcnt(0)");   // areg + B(t+1) landed
      __builtin_amdgcn_sched_barrier(0);
      CVTWRITE(S ^ 1);
      __builtin_amdgcn_sched_barrier(0);
      asm volatile("s_waitcnt lgkmcnt(0)"); // A writes retired before barrier
      __builtin_amdgcn_sched_barrier(0);
    }
    __builtin_amdgcn_s_barrier();           // S^1 consistent; S free next iter
  }

  // epilogue: vt[(n*B + b)*T + t], m = b*512 + t
  #pragma unroll
  for (int mi = 0; mi < 8; mi++)
    #pragma unroll
    for (int ni = 0; ni < 4; ni++){
      int n  = n0 + wc * 64 + ni * 16 + lr;
      int mb = m0 + wr * 128 + mi * 16 + kg * 4;
      int bb = mb >> 9, t = mb & 511;
      ushort4 o;
      o.x = f2bf(acc[mi][ni][0]); o.y = f2bf(acc[mi][ni][1]);
      o.z = f2bf(acc[mi][ni][2]); o.w = f2bf(acc[mi][ni][3]);
      *(ushort4*)&vt[((size_t)n * B_ + bb) * T_ + t] = o;
    }
}

// ---------------- conv via MFMA, PAIRED t-tiles + fused band table ----------------
// One block = one channel c + t-tile PAIR {t0b-128, t0b}, t0b in {128, 384}.
// Shared v staging + shared bfr reads; barrier iters 40->24 per channel, vt k-rows
// read 1280->768. acc doubled (two 128x128 output tiles). Causal skip for lower
// tile is block-uniform (k0 < t0b). Band layout/indexing r9/r14-verified.
__global__ __launch_bounds__(256) void conv_mfma2(
    const unsigned short* __restrict__ vt,    // (C, B, T) bf16
    const float* __restrict__ pw,             // (C)
    const float* __restrict__ line,           // (T)
    const float* __restrict__ gain,           // (1,1,C)
    unsigned short* __restrict__ Ybf)         // (C, B, T) bf16, gain+relu applied
{
  __shared__ short Bs[128 * 32];              // v tile: 128 b x 32 s (8KB)
  __shared__ short Ab[16 * 1280];             // up to 16 Toeplitz bands (40KB)
  __shared__ unsigned short zbuf[512];        // 1KB
  const int id  = blockIdx.x;                 // 2048 blocks
  const int xcd = id & 7;
  const int jj  = id >> 3;                    // 0..255
  const int c   = xcd + ((jj >> 1) << 3);     // 1024 channels
  const int pr  = jj & 1;                     // pair: 0 -> {0,128}, 1 -> {256,384}
  const int t0b = pr ? 384 : 128;
  const int t0a = t0b - 128;
  const int Kp  = t0b + 128;                  // 256 or 512
  const int tid = threadIdx.x, lane = tid & 63, wave = tid >> 6;
  const int wr = wave >> 1, wc = wave & 1, lr = lane & 15, kg = lane >> 4;
  const int nb = (t0b >> 5) + 4;              // bands needed: 8 or 16

  // ---- fused band computation
  {
    float p = pw[c];
    float e = 2.0f + 100.0f / (1.0f + expf(-p));
    for (int k = tid; k < Kp; k += 256){
      float lv = line[k];
      float z = (lv > 0.f) ? expf(e * logf(lv)) : 0.f;
      zbuf[k] = f2bf(z);
    }
  }
  __syncthreads();
  for (int idx = tid; idx < nb * 1280; idx += 256){
    int i = idx / 40, j = idx - i * 40;
    int d32 = i >> 5, ii = i & 31;
    int k = d32 * 32 + ii - j;
    unsigned short v = 0;
    if (j < 32 && k >= 0) v = zbuf[k];        // k < 32*nb = Kp always
    Ab[idx] = v;
  }
  // visibility: covered by iteration-0's __syncthreads() below

  f32x4 acca[4][4], accb[4][4];
  #pragma unroll
  for (int mi = 0; mi < 4; mi++)
    #pragma unroll
    for (int ni = 0; ni < 4; ni++){
      acca[mi][ni] = (f32x4){0.f, 0.f, 0.f, 0.f};
      accb[mi][ni] = (f32x4){0.f, 0.f, 0.f, 0.f};
    }

  const int r1 = tid >> 2, ch1 = tid & 3;
  char* bbase = (char*)Bs + (tid & ~63) * 16;
  const size_t vbase = (size_t)c * B_ * T_;

  for (int k0 = 0; k0 < Kp; k0 += 32){
    __syncthreads();
    gload16(vt + vbase + (size_t)r1 * T_        + k0 + ch1 * 8, bbase);
    gload16(vt + vbase + (size_t)(64 + r1) * T_ + k0 + ch1 * 8, bbase + 4096);
    __syncthreads();

    short8 bfr[4];
    #pragma unroll
    for (int ni = 0; ni < 4; ni++)
      bfr[ni] = *(const short8*)&Bs[(wc * 64 + ni * 16 + lr) * 32 + kg * 8];

    // ---- upper tile (t0b): always active
    {
      const int dbase = ((t0b - k0) >> 5) + wr * 2;
      #pragma unroll
      for (int mi = 0; mi < 4; mi++){
        const int d32 = dbase + (mi >> 1);       // wave-uniform per mi
        if (d32 >= 0){
          const int i = ((mi & 1) << 4) + lr;
          short8 afv = *(const short8*)&Ab[d32 * 1280 + i * 40 + kg * 8];
          #pragma unroll
          for (int ni = 0; ni < 4; ni++)
            accb[mi][ni] = __builtin_amdgcn_mfma_f32_16x16x32_bf16(afv, bfr[ni], accb[mi][ni], 0, 0, 0);
        }
      }
    }
    // ---- lower tile (t0a): active while k0 < t0a + 128 == t0b (block-uniform)
    if (k0 < t0b){
      const int dbase = ((t0a - k0) >> 5) + wr * 2;
      #pragma unroll
      for (int mi = 0; mi < 4; mi++){
        const int d32 = dbase + (mi >> 1);
        if (d32 >= 0){
          const int i = ((mi & 1) << 4) + lr;
          short8 afv = *(const short8*)&Ab[d32 * 1280 + i * 40 + kg * 8];
          #pragma unroll
          for (int ni = 0; ni < 4; ni++)
            acca[mi][ni] = __builtin_amdgcn_mfma_f32_16x16x32_bf16(afv, bfr[ni], acca[mi][ni], 0, 0, 0);
        }
      }
    }
  }

  const float g = gain[c];
  #pragma unroll
  for (int mi = 0; mi < 4; mi++)
    #pragma unroll
    for (int ni = 0; ni < 4; ni++){
      int b = wc * 64 + ni * 16 + lr;
      int ta = t0a + wr * 64 + mi * 16 + kg * 4;
      int tb = t0b + wr * 64 + mi * 16 + kg * 4;
      ushort4 oa, ob;
      oa.x = f2bf(fmaxf(acca[mi][ni][0] * g, 0.f));
      oa.y = f2bf(fmaxf(acca[mi][ni][1] * g, 0.f));
      oa.z = f2bf(fmaxf(acca[mi][ni][2] * g, 0.f));
      oa.w = f2bf(fmaxf(acca[mi][ni][3] * g, 0.f));
      ob.x = f2bf(fmaxf(accb[mi][ni][0] * g, 0.f));
      ob.y = f2bf(fmaxf(accb[mi][ni][1] * g, 0.f));
      ob.z = f2bf(fmaxf(accb[mi][ni][2] * g, 0.f));
      ob.w = f2bf(fmaxf(accb[mi][ni][3] * g, 0.f));
      *(ushort4*)&Ybf[((size_t)c * B_ + b) * T_ + ta] = oa;
      *(ushort4*)&Ybf[((size_t)c * B_ + b) * T_ + tb] = ob;
    }
}

// ---------------- final: (C,B,T) bf16 -> (B,T,C) f32 ----------------
__global__ __launch_bounds__(256) void final_out(const unsigned short* __restrict__ Ybf,
                                                 float* __restrict__ out){
  __shared__ unsigned short tile[64][72];
  const int c0 = blockIdx.x * 64;
  const int t0 = blockIdx.y * 64;
  const int b  = blockIdx.z;
  const int tid = threadIdx.x;
  const int cr = tid >> 4;
  const int t4 = (tid & 15) * 4;
  for (int q = 0; q < 64; q += 16){
    ushort4 u = *(const ushort4*)&Ybf[((size_t)(c0 + cr + q) * B_ + b) * T_ + t0 + t4];
    *(ushort4*)&tile[cr + q][t4] = u;
  }
  __syncthreads();
  const int tr = tid >> 4;
  const int c4 = (tid & 15) * 4;
  for (int q = 0; q < 64; q += 16){
    int t = tr + q;
    float4 o;
    o.x = __uint_as_float((unsigned)tile[c4 + 0][t] << 16);
    o.y = __uint_as_float((unsigned)tile[c4 + 1][t] << 16);
    o.z = __uint_as_float((unsigned)tile[c4 + 2][t] << 16);
    o.w = __uint_as_float((unsigned)tile[c4 + 3][t] << 16);
    *(float4*)&out[((size_t)b * T_ + t0 + t) * C_ + c0 + c4] = o;
  }
}

extern "C" void kernel_launch(void* const* d_in, const int* in_sizes, int n_in,
                              void* d_out, int out_size, void* d_ws, size_t ws_size,
                              hipStream_t stream)
{
  (void)in_sizes; (void)n_in; (void)out_size; (void)ws_size;
  const float* x    = (const float*)d_in[0];
  const float* Wp   = (const float*)d_in[1];
  const float* Wv   = (const float*)d_in[2];
  const float* gain = (const float*)d_in[3];
  const float* pw   = (const float*)d_in[4];
  const float* line = (const float*)d_in[5];
  float* out = (float*)d_out;

  // ws: [Ybf 128MB][WpT 2MB][Wv_bf 2MB][W_f 2MB]
  char* ws = (char*)d_ws;
  unsigned short* Ybf   = (unsigned short*)ws;
  unsigned short* WpT   = (unsigned short*)(ws + 134217728);
  unsigned short* Wv_bf = (unsigned short*)(ws + 134217728 + 2097152);
  unsigned short* W_f   = (unsigned short*)(ws + 134217728 + 2 * 2097152);
  // d_out (256MB f32) reused as scratch:
  unsigned short* vt    = (unsigned short*)d_out + 67108864;         // upper 128MB (dead after conv)

  // weights
  cast_f32_bf16<<<256, 256, 0, stream>>>(Wv, Wv_bf, (long)C_ * C_);
  transpose_cast<<<dim3(32, 32), dim3(32, 8), 0, stream>>>(Wp, WpT);
  gemm_bt_bf16<<<dim3(8, 8), 256, 0, stream>>>(Wv_bf, WpT, W_f, C_, C_, C_);
  // v = x @ W_f^T with fused f32->bf16 A-staging + lgkm ladder; writes (C,B,T)
  gemm256_fused<<<1024, 512, 131072, stream>>>(x, W_f, vt);
  // conv + gain + relu -> Ybf (C,B,T); paired t-tiles, band table in-kernel
  conv_mfma2<<<2048, 256, 0, stream>>>(vt, pw, line, gain, Ybf);
  // transpose to (B,T,C) f32
  final_out<<<dim3(16, 8, 128), 256, 0, stream>>>(Ybf, out);
}

// Round 16
// 437.857 us; speedup vs baseline: 1.1620x; 1.1620x over previous
//
#include <hip/hip_runtime.h>
#include <hip/hip_bf16.h>

#define B_ 128
#define T_ 512
#define C_ 1024

typedef __attribute__((ext_vector_type(8))) short short8;
typedef __attribute__((ext_vector_type(4))) float f32x4;

__device__ __forceinline__ unsigned short f2bf(float f){
  unsigned u; __builtin_memcpy(&u, &f, 4);
  u += 0x7FFFu + ((u >> 16) & 1u);          // RNE
  return (unsigned short)(u >> 16);
}

// ---- async global->LDS 16B (LDS dest: wave-uniform base + lane*16)
typedef __attribute__((address_space(3))) unsigned lds_u32_t;
typedef __attribute__((address_space(1))) unsigned glb_u32_t;
typedef __attribute__((address_space(3))) char lds_char;
__device__ __forceinline__ void gload16(const void* g, void* l){
  __builtin_amdgcn_global_load_lds((const glb_u32_t*)g, (lds_u32_t*)l, 16, 0, 0);
}

// ---------------- cast f32 -> bf16 (vectorized; weights only) ----------------
__global__ void cast_f32_bf16(const float* __restrict__ in, unsigned short* __restrict__ out, long n){
  long i = (long)blockIdx.x * blockDim.x + threadIdx.x;
  long stride = (long)gridDim.x * blockDim.x;
  for (long j = i * 4; j < n; j += stride * 4){
    float4 v = *(const float4*)(in + j);
    ushort4 o; o.x = f2bf(v.x); o.y = f2bf(v.y); o.z = f2bf(v.z); o.w = f2bf(v.w);
    *(ushort4*)(out + j) = o;
  }
}

// ---------------- transpose-cast W_proj (e,c) -> WpT (c,e) bf16 ----------------
__global__ void transpose_cast(const float* __restrict__ in, unsigned short* __restrict__ out){
  __shared__ float tile[32][33];
  int c0 = blockIdx.x * 32, e0 = blockIdx.y * 32;
  int tx = threadIdx.x, ty = threadIdx.y;     // (32,8)
  for (int r = 0; r < 32; r += 8)
    tile[ty + r][tx] = in[(size_t)(e0 + ty + r) * C_ + c0 + tx];
  __syncthreads();
  for (int r = 0; r < 32; r += 8)
    out[(size_t)(c0 + ty + r) * C_ + e0 + tx] = f2bf(tile[tx][ty + r]);
}

// ---------------- small bf16 GEMM (weight fuse), m97-style 128x128 ----------------
__global__ __launch_bounds__(256) void gemm_bt_bf16(
    const unsigned short* __restrict__ A,   // M x K
    const unsigned short* __restrict__ Bt,  // N x K
    unsigned short* __restrict__ Cc,        // M x N
    int M, int N, int K)
{
  __shared__ short As[128 * 32];
  __shared__ short Bs[128 * 32];
  const int tid  = threadIdx.x;
  const int lane = tid & 63;
  const int wave = tid >> 6;
  const int wr = wave >> 1, wc = wave & 1;
  const int lr = lane & 15, kg = lane >> 4;
  const int m0 = blockIdx.x * 128;
  const int n0 = blockIdx.y * 128;

  f32x4 acc[4][4];
  #pragma unroll
  for (int mi = 0; mi < 4; mi++)
    #pragma unroll
    for (int ni = 0; ni < 4; ni++)
      acc[mi][ni] = (f32x4){0.f, 0.f, 0.f, 0.f};

  const int r1 = tid >> 2, ch1 = tid & 3;
  char* abase = (char*)As + (tid & ~63) * 16;
  char* bbase = (char*)Bs + (tid & ~63) * 16;

  for (int k0 = 0; k0 < K; k0 += 32){
    __syncthreads();
    gload16(A  + (size_t)(m0 + r1)      * K + k0 + ch1 * 8, abase);
    gload16(A  + (size_t)(m0 + 64 + r1) * K + k0 + ch1 * 8, abase + 4096);
    gload16(Bt + (size_t)(n0 + r1)      * K + k0 + ch1 * 8, bbase);
    gload16(Bt + (size_t)(n0 + 64 + r1) * K + k0 + ch1 * 8, bbase + 4096);
    __syncthreads();

    short8 af[4], bfr[4];
    #pragma unroll
    for (int mi = 0; mi < 4; mi++)
      af[mi] = *(const short8*)&As[(wr * 64 + mi * 16 + lr) * 32 + kg * 8];
    #pragma unroll
    for (int ni = 0; ni < 4; ni++)
      bfr[ni] = *(const short8*)&Bs[(wc * 64 + ni * 16 + lr) * 32 + kg * 8];
    #pragma unroll
    for (int mi = 0; mi < 4; mi++)
      #pragma unroll
      for (int ni = 0; ni < 4; ni++)
        acc[mi][ni] = __builtin_amdgcn_mfma_f32_16x16x32_bf16(af[mi], bfr[ni], acc[mi][ni], 0, 0, 0);
  }

  #pragma unroll
  for (int mi = 0; mi < 4; mi++)
    #pragma unroll
    for (int ni = 0; ni < 4; ni++){
      int n = n0 + wc * 64 + ni * 16 + lr;
      int mb = m0 + wr * 64 + mi * 16 + kg * 4;
      #pragma unroll
      for (int j = 0; j < 4; j++)
        Cc[(size_t)(mb + j) * N + n] = f2bf(acc[mi][ni][j]);
    }
}

// ======= 256x256 GEMM, FUSED f32->bf16 A-staging + lgkm LADDER (r15-exact, 244us) =======
#define SWZ(x) ((x) ^ ((((x) >> 7) & 3) << 4))

#define STAGE_B(kt, kh) { \
  int d_ = wv * 1024 + ln * 16; int o_ = SWZ(d_); \
  gload16(Bg + (size_t)(n0 + (o_ >> 6)) * 1024 + (kt) * 64 + (kh) * 32 + ((o_ >> 4) & 3) * 8, \
          ldsc + 65536 + ((kt) & 1) * 32768 + (kh) * 16384 + wv * 1024); \
  d_ += 8192; o_ = SWZ(d_); \
  gload16(Bg + (size_t)(n0 + (o_ >> 6)) * 1024 + (kt) * 64 + (kh) * 32 + ((o_ >> 4) & 3) * 8, \
          ldsc + 65536 + ((kt) & 1) * 32768 + (kh) * 16384 + 8192 + wv * 1024); }

#define LOADA(kt) { \
  _Pragma("unroll") for (int kh = 0; kh < 2; kh++) \
    _Pragma("unroll") for (int hf = 0; hf < 2; hf++){ \
      const float* p_ = Ag32 + (size_t)(m0 + rowA + hf * 128) * 1024 + (kt) * 64 + kh * 32 + c8 * 8; \
      areg[kh][hf][0] = *(const float4*)p_; \
      areg[kh][hf][1] = *(const float4*)(p_ + 4); } }

#define CVTWRITE(slot) { \
  _Pragma("unroll") for (int kh = 0; kh < 2; kh++) \
    _Pragma("unroll") for (int hf = 0; hf < 2; hf++){ \
      short8 w_; \
      _Pragma("unroll") for (int q = 0; q < 4; q++){ \
        w_[q]     = (short)f2bf(areg[kh][hf][0][q]); \
        w_[q + 4] = (short)f2bf(areg[kh][hf][1][q]); } \
      int d_ = wv * 1024 + ln * 16 + hf * 8192; \
      unsigned ad_ = (unsigned)(size_t)(lds3 + (slot) * 32768 + kh * 16384 + SWZ(d_)); \
      asm volatile("ds_write_b128 %0, %1" :: "v"(ad_), "v"(w_)); } }

#define MFMA4(MI) { \
  acc[MI][0] = __builtin_amdgcn_mfma_f32_16x16x32_bf16(af[MI], bfr[0], acc[MI][0], 0, 0, 0); \
  acc[MI][1] = __builtin_amdgcn_mfma_f32_16x16x32_bf16(af[MI], bfr[1], acc[MI][1], 0, 0, 0); \
  acc[MI][2] = __builtin_amdgcn_mfma_f32_16x16x32_bf16(af[MI], bfr[2], acc[MI][2], 0, 0, 0); \
  acc[MI][3] = __builtin_amdgcn_mfma_f32_16x16x32_bf16(af[MI], bfr[3], acc[MI][3], 0, 0, 0); }

#define LSTEP(N, MI) { \
  asm volatile("s_waitcnt lgkmcnt(" #N ")"); \
  __builtin_amdgcn_sched_barrier(0); \
  MFMA4(MI); }

#define KHALF(S, KHOFF) { \
  _Pragma("unroll") for (int ni = 0; ni < 4; ni++){ \
    int off = 65536 + (S) * 32768 + (KHOFF) + (wc * 64 + ni * 16 + lr) * 64 + kg * 16; \
    unsigned a_ = (unsigned)(size_t)(lds3 + SWZ(off)); \
    asm volatile("ds_read_b128 %0, %1" : "=v"(bfr[ni]) : "v"(a_)); } \
  _Pragma("unroll") for (int mi = 0; mi < 8; mi++){ \
    int off = (S) * 32768 + (KHOFF) + (wr * 128 + mi * 16 + lr) * 64 + kg * 16; \
    unsigned a_ = (unsigned)(size_t)(lds3 + SWZ(off)); \
    asm volatile("ds_read_b128 %0, %1" : "=v"(af[mi]) : "v"(a_)); } \
  __builtin_amdgcn_s_setprio(1); \
  LSTEP(7, 0) LSTEP(6, 1) LSTEP(5, 2) LSTEP(4, 3) \
  LSTEP(3, 4) LSTEP(2, 5) LSTEP(1, 6) LSTEP(0, 7) \
  __builtin_amdgcn_s_setprio(0); \
  __builtin_amdgcn_sched_barrier(0); }

__global__ __launch_bounds__(512, 2) void gemm256_fused(
    const float* __restrict__ Ag32,         // 65536 x 1024 f32 (x)
    const unsigned short* __restrict__ Bg,  // 1024 x 1024 bf16 (W_f)
    unsigned short* __restrict__ vt)        // (C, B, T)
{
  extern __shared__ char ldsc[];            // 131072 B
  lds_char* lds3 = (lds_char*)ldsc;
  const int tid = threadIdx.x;
  const int ln  = tid & 63;
  const int wv  = tid >> 6;                 // 8 waves
  const int wr  = wv >> 2;                  // 2 M-waves (128 rows each)
  const int wc  = wv & 3;                   // 4 N-waves (64 cols each)
  const int lr  = ln & 15, kg = ln >> 4;
  const int rowA = wv * 16 + (ln >> 2);
  const int c8   = ln & 3;
  const int id  = blockIdx.x;
  const int jj  = (id & 7) * 128 + (id >> 3);
  const int n0  = (jj & 3) * 256;
  const int m0  = (jj >> 2) * 256;

  f32x4 acc[8][4];
  #pragma unroll
  for (int mi = 0; mi < 8; mi++)
    #pragma unroll
    for (int ni = 0; ni < 4; ni++)
      acc[mi][ni] = (f32x4){0.f, 0.f, 0.f, 0.f};

  float4 areg[2][2][2];

  LOADA(0);
  asm volatile("s_waitcnt vmcnt(0)");
  __builtin_amdgcn_sched_barrier(0);
  CVTWRITE(0);
  __builtin_amdgcn_sched_barrier(0);
  STAGE_B(0, 0); STAGE_B(0, 1);
  __builtin_amdgcn_sched_barrier(0);
  asm volatile("s_waitcnt lgkmcnt(0)");
  __builtin_amdgcn_sched_barrier(0);
  asm volatile("s_waitcnt vmcnt(0)");
  __builtin_amdgcn_sched_barrier(0);
  __builtin_amdgcn_s_barrier();

  short8 af[8], bfr[4];

  #pragma unroll 1
  for (int t = 0; t < 16; ++t){
    const int S = t & 1;

    if (t < 15){
      LOADA(t + 1);
      __builtin_amdgcn_sched_barrier(0);
      STAGE_B(t + 1, 0); STAGE_B(t + 1, 1);
      __builtin_amdgcn_sched_barrier(0);
    }

    KHALF(S, 0)
    KHALF(S, 16384)

    if (t < 15){
      asm volatile("s_waitcnt vmcnt(0)");
      __builtin_amdgcn_sched_barrier(0);
      CVTWRITE(S ^ 1);
      __builtin_amdgcn_sched_barrier(0);
      asm volatile("s_waitcnt lgkmcnt(0)");
      __builtin_amdgcn_sched_barrier(0);
    }
    __builtin_amdgcn_s_barrier();
  }

  #pragma unroll
  for (int mi = 0; mi < 8; mi++)
    #pragma unroll
    for (int ni = 0; ni < 4; ni++){
      int n  = n0 + wc * 64 + ni * 16 + lr;
      int mb = m0 + wr * 128 + mi * 16 + kg * 4;
      int bb = mb >> 9, t = mb & 511;
      ushort4 o;
      o.x = f2bf(acc[mi][ni][0]); o.y = f2bf(acc[mi][ni][1]);
      o.z = f2bf(acc[mi][ni][2]); o.w = f2bf(acc[mi][ni][3]);
      *(ushort4*)&vt[((size_t)n * B_ + bb) * T_ + t] = o;
    }
}

// ---------------- conv via MFMA v3: T14 reg-staged vt (no per-iter DMA drain) ----------
// r14 structure/indexing, but the vt tile is prefetched into REGISTERS one iteration
// ahead (plain short8 loads; latency hides under reads+MFMA+barrier) and ds_write'n
// into the single 8KB Bs at iter top. LDS stays 49KB -> 3 blocks/CU. Loop LDS ops all
// inline-asm (r6 legalizer discipline). Per-lane write addr = Bs + tid*16 (gload16-equiv).
__global__ __launch_bounds__(256) void conv_mfma3(
    const unsigned short* __restrict__ vt,    // (C, B, T) bf16
    const float* __restrict__ pw,             // (C)
    const float* __restrict__ line,           // (T)
    const float* __restrict__ gain,           // (1,1,C)
    unsigned short* __restrict__ Ybf)         // (C, B, T) bf16, gain+relu applied
{
  __shared__ short Bs[128 * 32];              // v tile: 128 b x 32 s (8KB), single buffer
  __shared__ short Ab[16 * 1280];             // Toeplitz bands (40KB)
  __shared__ unsigned short zbuf[512];        // 1KB
  lds_char* ldsB = (lds_char*)Bs;
  lds_char* ldsA = (lds_char*)Ab;
  const int id  = blockIdx.x;                 // 4096 blocks
  const int xcd = id & 7;
  const int jj  = id >> 3;                    // 0..511
  const int c   = xcd + ((jj >> 2) << 3);     // 1024 channels
  const int t0  = (jj & 3) << 7;              // 4 t-tiles
  const int tid = threadIdx.x, lane = tid & 63, wave = tid >> 6;
  const int wr = wave >> 1, wc = wave & 1, lr = lane & 15, kg = lane >> 4;
  const int K  = t0 + 128;                    // causal: s < t0+128
  const int nIter = K >> 5;
  const int nb = (t0 >> 5) + 4;               // bands d32 = 0..nb-1

  // ---- fused band computation (r14-verified)
  {
    float p = pw[c];
    float e = 2.0f + 100.0f / (1.0f + expf(-p));
    for (int k = tid; k < K; k += 256){
      float lv = line[k];
      float z = (lv > 0.f) ? expf(e * logf(lv)) : 0.f;
      zbuf[k] = f2bf(z);
    }
  }
  __syncthreads();
  for (int idx = tid; idx < nb * 1280; idx += 256){
    int i = idx / 40, j = idx - i * 40;
    int d32 = i >> 5, ii = i & 31;
    int k = d32 * 32 + ii - j;
    unsigned short v = 0;
    if (j < 32 && k >= 0) v = zbuf[k];
    Ab[idx] = v;
  }
  // visibility of Ab: covered by iter-0's lgkm(0)+barrier below

  f32x4 acc[4][4];
  #pragma unroll
  for (int mi = 0; mi < 4; mi++)
    #pragma unroll
    for (int ni = 0; ni < 4; ni++)
      acc[mi][ni] = (f32x4){0.f, 0.f, 0.f, 0.f};

  const int r1 = tid >> 2, ch1 = tid & 3;
  const size_t vbase = (size_t)c * B_ * T_;
  const unsigned adw0 = (unsigned)(size_t)(ldsB + tid * 16);
  const unsigned adw1 = adw0 + 4096;

  // tile 0 -> regs
  short8 va0 = *(const short8*)&vt[vbase + (size_t)r1 * T_        + ch1 * 8];
  short8 va1 = *(const short8*)&vt[vbase + (size_t)(64 + r1) * T_ + ch1 * 8];

  #pragma unroll 1
  for (int it = 0; it < nIter; ++it){
    const int k0 = it << 5;
    // write tile it (regs) -> Bs  (compiler auto-waits the va loads)
    asm volatile("ds_write_b128 %0, %1" :: "v"(adw0), "v"(va0));
    asm volatile("ds_write_b128 %0, %1" :: "v"(adw1), "v"(va1));
    asm volatile("s_waitcnt lgkmcnt(0)");
    __builtin_amdgcn_sched_barrier(0);
    __builtin_amdgcn_s_barrier();             // all writes visible (+Ab on iter 0)

    // prefetch tile it+1 -> regs (latency hidden under reads+MFMA+barrier)
    if (it + 1 < nIter){
      va0 = *(const short8*)&vt[vbase + (size_t)r1 * T_        + k0 + 32 + ch1 * 8];
      va1 = *(const short8*)&vt[vbase + (size_t)(64 + r1) * T_ + k0 + 32 + ch1 * 8];
    }

    short8 bfr[4], afv[4];
    #pragma unroll
    for (int ni = 0; ni < 4; ni++){
      unsigned a_ = (unsigned)(size_t)(ldsB + (wc * 64 + ni * 16 + lr) * 64 + kg * 16);
      asm volatile("ds_read_b128 %0, %1" : "=v"(bfr[ni]) : "v"(a_));
    }
    const int dbase = ((t0 - k0) >> 5) + wr * 2;
    #pragma unroll
    for (int mi = 0; mi < 4; mi++){
      int d32 = dbase + (mi >> 1);
      int d32c = d32 < 0 ? 0 : d32;
      int i = ((mi & 1) << 4) + lr;
      unsigned a_ = (unsigned)(size_t)(ldsA + (d32c * 1280 + i * 40 + kg * 8) * 2);
      asm volatile("ds_read_b128 %0, %1" : "=v"(afv[mi]) : "v"(a_));
    }
    asm volatile("s_waitcnt lgkmcnt(0)");
    __builtin_amdgcn_sched_barrier(0);
    __builtin_amdgcn_s_setprio(1);
    #pragma unroll
    for (int mi = 0; mi < 4; mi++){
      if (dbase + (mi >> 1) >= 0){              // wave-uniform causal skip
        #pragma unroll
        for (int ni = 0; ni < 4; ni++)
          acc[mi][ni] = __builtin_amdgcn_mfma_f32_16x16x32_bf16(afv[mi], bfr[ni], acc[mi][ni], 0, 0, 0);
      }
    }
    __builtin_amdgcn_s_setprio(0);
    __builtin_amdgcn_sched_barrier(0);
    __builtin_amdgcn_s_barrier();               // reads done before next iter's writes
  }

  const float g = gain[c];
  #pragma unroll
  for (int mi = 0; mi < 4; mi++)
    #pragma unroll
    for (int ni = 0; ni < 4; ni++){
      int t = t0 + wr * 64 + mi * 16 + kg * 4;
      int b = wc * 64 + ni * 16 + lr;
      ushort4 o;
      o.x = f2bf(fmaxf(acc[mi][ni][0] * g, 0.f));
      o.y = f2bf(fmaxf(acc[mi][ni][1] * g, 0.f));
      o.z = f2bf(fmaxf(acc[mi][ni][2] * g, 0.f));
      o.w = f2bf(fmaxf(acc[mi][ni][3] * g, 0.f));
      *(ushort4*)&Ybf[((size_t)c * B_ + b) * T_ + t] = o;
    }
}

// ---------------- final: (C,B,T) bf16 -> (B,T,C) f32 ----------------
__global__ __launch_bounds__(256) void final_out(const unsigned short* __restrict__ Ybf,
                                                 float* __restrict__ out){
  __shared__ unsigned short tile[64][72];
  const int c0 = blockIdx.x * 64;
  const int t0 = blockIdx.y * 64;
  const int b  = blockIdx.z;
  const int tid = threadIdx.x;
  const int cr = tid >> 4;
  const int t4 = (tid & 15) * 4;
  for (int q = 0; q < 64; q += 16){
    ushort4 u = *(const ushort4*)&Ybf[((size_t)(c0 + cr + q) * B_ + b) * T_ + t0 + t4];
    *(ushort4*)&tile[cr + q][t4] = u;
  }
  __syncthreads();
  const int tr = tid >> 4;
  const int c4 = (tid & 15) * 4;
  for (int q = 0; q < 64; q += 16){
    int t = tr + q;
    float4 o;
    o.x = __uint_as_float((unsigned)tile[c4 + 0][t] << 16);
    o.y = __uint_as_float((unsigned)tile[c4 + 1][t] << 16);
    o.z = __uint_as_float((unsigned)tile[c4 + 2][t] << 16);
    o.w = __uint_as_float((unsigned)tile[c4 + 3][t] << 16);
    *(float4*)&out[((size_t)b * T_ + t0 + t) * C_ + c0 + c4] = o;
  }
}

extern "C" void kernel_launch(void* const* d_in, const int* in_sizes, int n_in,
                              void* d_out, int out_size, void* d_ws, size_t ws_size,
                              hipStream_t stream)
{
  (void)in_sizes; (void)n_in; (void)out_size; (void)ws_size;
  const float* x    = (const float*)d_in[0];
  const float* Wp   = (const float*)d_in[1];
  const float* Wv   = (const float*)d_in[2];
  const float* gain = (const float*)d_in[3];
  const float* pw   = (const float*)d_in[4];
  const float* line = (const float*)d_in[5];
  float* out = (float*)d_out;

  // ws: [Ybf 128MB][WpT 2MB][Wv_bf 2MB][W_f 2MB]
  char* ws = (char*)d_ws;
  unsigned short* Ybf   = (unsigned short*)ws;
  unsigned short* WpT   = (unsigned short*)(ws + 134217728);
  unsigned short* Wv_bf = (unsigned short*)(ws + 134217728 + 2097152);
  unsigned short* W_f   = (unsigned short*)(ws + 134217728 + 2 * 2097152);
  // d_out (256MB f32) reused as scratch:
  unsigned short* vt    = (unsigned short*)d_out + 67108864;         // upper 128MB (dead after conv)

  // weights
  cast_f32_bf16<<<256, 256, 0, stream>>>(Wv, Wv_bf, (long)C_ * C_);
  transpose_cast<<<dim3(32, 32), dim3(32, 8), 0, stream>>>(Wp, WpT);
  gemm_bt_bf16<<<dim3(8, 8), 256, 0, stream>>>(Wv_bf, WpT, W_f, C_, C_, C_);
  // v = x @ W_f^T with fused f32->bf16 A-staging + lgkm ladder (r15-exact)
  gemm256_fused<<<1024, 512, 131072, stream>>>(x, W_f, vt);
  // conv + gain + relu -> Ybf (C,B,T); reg-staged vt pipeline, band table in-kernel
  conv_mfma3<<<4096, 256, 0, stream>>>(vt, pw, line, gain, Ybf);
  // transpose to (B,T,C) f32
  final_out<<<dim3(16, 8, 128), 256, 0, stream>>>(Ybf, out);
}

// Round 17
// 421.065 us; speedup vs baseline: 1.2084x; 1.0399x over previous
//
#include <hip/hip_runtime.h>
#include <hip/hip_bf16.h>

#define B_ 128
#define T_ 512
#define C_ 1024

typedef __attribute__((ext_vector_type(8))) short short8;
typedef __attribute__((ext_vector_type(4))) float f32x4;

__device__ __forceinline__ unsigned short f2bf(float f){
  unsigned u; __builtin_memcpy(&u, &f, 4);
  u += 0x7FFFu + ((u >> 16) & 1u);          // RNE
  return (unsigned short)(u >> 16);
}

// ---- async global->LDS 16B (LDS dest: wave-uniform base + lane*16)
typedef __attribute__((address_space(3))) unsigned lds_u32_t;
typedef __attribute__((address_space(1))) unsigned glb_u32_t;
typedef __attribute__((address_space(3))) char lds_char;
__device__ __forceinline__ void gload16(const void* g, void* l){
  __builtin_amdgcn_global_load_lds((const glb_u32_t*)g, (lds_u32_t*)l, 16, 0, 0);
}

// ---------------- cast f32 -> bf16 (vectorized; weights only) ----------------
__global__ void cast_f32_bf16(const float* __restrict__ in, unsigned short* __restrict__ out, long n){
  long i = (long)blockIdx.x * blockDim.x + threadIdx.x;
  long stride = (long)gridDim.x * blockDim.x;
  for (long j = i * 4; j < n; j += stride * 4){
    float4 v = *(const float4*)(in + j);
    ushort4 o; o.x = f2bf(v.x); o.y = f2bf(v.y); o.z = f2bf(v.z); o.w = f2bf(v.w);
    *(ushort4*)(out + j) = o;
  }
}

// ---------------- transpose-cast W_proj (e,c) -> WpT (c,e) bf16 ----------------
__global__ void transpose_cast(const float* __restrict__ in, unsigned short* __restrict__ out){
  __shared__ float tile[32][33];
  int c0 = blockIdx.x * 32, e0 = blockIdx.y * 32;
  int tx = threadIdx.x, ty = threadIdx.y;     // (32,8)
  for (int r = 0; r < 32; r += 8)
    tile[ty + r][tx] = in[(size_t)(e0 + ty + r) * C_ + c0 + tx];
  __syncthreads();
  for (int r = 0; r < 32; r += 8)
    out[(size_t)(c0 + ty + r) * C_ + e0 + tx] = f2bf(tile[tx][ty + r]);
}

// ---------------- small bf16 GEMM (weight fuse), m97-style 128x128 ----------------
__global__ __launch_bounds__(256) void gemm_bt_bf16(
    const unsigned short* __restrict__ A,   // M x K
    const unsigned short* __restrict__ Bt,  // N x K
    unsigned short* __restrict__ Cc,        // M x N
    int M, int N, int K)
{
  __shared__ short As[128 * 32];
  __shared__ short Bs[128 * 32];
  const int tid  = threadIdx.x;
  const int lane = tid & 63;
  const int wave = tid >> 6;
  const int wr = wave >> 1, wc = wave & 1;
  const int lr = lane & 15, kg = lane >> 4;
  const int m0 = blockIdx.x * 128;
  const int n0 = blockIdx.y * 128;

  f32x4 acc[4][4];
  #pragma unroll
  for (int mi = 0; mi < 4; mi++)
    #pragma unroll
    for (int ni = 0; ni < 4; ni++)
      acc[mi][ni] = (f32x4){0.f, 0.f, 0.f, 0.f};

  const int r1 = tid >> 2, ch1 = tid & 3;
  char* abase = (char*)As + (tid & ~63) * 16;
  char* bbase = (char*)Bs + (tid & ~63) * 16;

  for (int k0 = 0; k0 < K; k0 += 32){
    __syncthreads();
    gload16(A  + (size_t)(m0 + r1)      * K + k0 + ch1 * 8, abase);
    gload16(A  + (size_t)(m0 + 64 + r1) * K + k0 + ch1 * 8, abase + 4096);
    gload16(Bt + (size_t)(n0 + r1)      * K + k0 + ch1 * 8, bbase);
    gload16(Bt + (size_t)(n0 + 64 + r1) * K + k0 + ch1 * 8, bbase + 4096);
    __syncthreads();

    short8 af[4], bfr[4];
    #pragma unroll
    for (int mi = 0; mi < 4; mi++)
      af[mi] = *(const short8*)&As[(wr * 64 + mi * 16 + lr) * 32 + kg * 8];
    #pragma unroll
    for (int ni = 0; ni < 4; ni++)
      bfr[ni] = *(const short8*)&Bs[(wc * 64 + ni * 16 + lr) * 32 + kg * 8];
    #pragma unroll
    for (int mi = 0; mi < 4; mi++)
      #pragma unroll
      for (int ni = 0; ni < 4; ni++)
        acc[mi][ni] = __builtin_amdgcn_mfma_f32_16x16x32_bf16(af[mi], bfr[ni], acc[mi][ni], 0, 0, 0);
  }

  #pragma unroll
  for (int mi = 0; mi < 4; mi++)
    #pragma unroll
    for (int ni = 0; ni < 4; ni++){
      int n = n0 + wc * 64 + ni * 16 + lr;
      int mb = m0 + wr * 64 + mi * 16 + kg * 4;
      #pragma unroll
      for (int j = 0; j < 4; j++)
        Cc[(size_t)(mb + j) * N + n] = f2bf(acc[mi][ni][j]);
    }
}

// ======= 256x256 GEMM, FUSED f32->bf16 A-staging + lgkm LADDER (r15/r16-exact) =======
#define SWZ(x) ((x) ^ ((((x) >> 7) & 3) << 4))

#define STAGE_B(kt, kh) { \
  int d_ = wv * 1024 + ln * 16; int o_ = SWZ(d_); \
  gload16(Bg + (size_t)(n0 + (o_ >> 6)) * 1024 + (kt) * 64 + (kh) * 32 + ((o_ >> 4) & 3) * 8, \
          ldsc + 65536 + ((kt) & 1) * 32768 + (kh) * 16384 + wv * 1024); \
  d_ += 8192; o_ = SWZ(d_); \
  gload16(Bg + (size_t)(n0 + (o_ >> 6)) * 1024 + (kt) * 64 + (kh) * 32 + ((o_ >> 4) & 3) * 8, \
          ldsc + 65536 + ((kt) & 1) * 32768 + (kh) * 16384 + 8192 + wv * 1024); }

#define LOADA(kt) { \
  _Pragma("unroll") for (int kh = 0; kh < 2; kh++) \
    _Pragma("unroll") for (int hf = 0; hf < 2; hf++){ \
      const float* p_ = Ag32 + (size_t)(m0 + rowA + hf * 128) * 1024 + (kt) * 64 + kh * 32 + c8 * 8; \
      areg[kh][hf][0] = *(const float4*)p_; \
      areg[kh][hf][1] = *(const float4*)(p_ + 4); } }

#define CVTWRITE(slot) { \
  _Pragma("unroll") for (int kh = 0; kh < 2; kh++) \
    _Pragma("unroll") for (int hf = 0; hf < 2; hf++){ \
      short8 w_; \
      _Pragma("unroll") for (int q = 0; q < 4; q++){ \
        w_[q]     = (short)f2bf(areg[kh][hf][0][q]); \
        w_[q + 4] = (short)f2bf(areg[kh][hf][1][q]); } \
      int d_ = wv * 1024 + ln * 16 + hf * 8192; \
      unsigned ad_ = (unsigned)(size_t)(lds3 + (slot) * 32768 + kh * 16384 + SWZ(d_)); \
      asm volatile("ds_write_b128 %0, %1" :: "v"(ad_), "v"(w_)); } }

#define MFMA4(MI) { \
  acc[MI][0] = __builtin_amdgcn_mfma_f32_16x16x32_bf16(af[MI], bfr[0], acc[MI][0], 0, 0, 0); \
  acc[MI][1] = __builtin_amdgcn_mfma_f32_16x16x32_bf16(af[MI], bfr[1], acc[MI][1], 0, 0, 0); \
  acc[MI][2] = __builtin_amdgcn_mfma_f32_16x16x32_bf16(af[MI], bfr[2], acc[MI][2], 0, 0, 0); \
  acc[MI][3] = __builtin_amdgcn_mfma_f32_16x16x32_bf16(af[MI], bfr[3], acc[MI][3], 0, 0, 0); }

#define LSTEP(N, MI) { \
  asm volatile("s_waitcnt lgkmcnt(" #N ")"); \
  __builtin_amdgcn_sched_barrier(0); \
  MFMA4(MI); }

#define KHALF(S, KHOFF) { \
  _Pragma("unroll") for (int ni = 0; ni < 4; ni++){ \
    int off = 65536 + (S) * 32768 + (KHOFF) + (wc * 64 + ni * 16 + lr) * 64 + kg * 16; \
    unsigned a_ = (unsigned)(size_t)(lds3 + SWZ(off)); \
    asm volatile("ds_read_b128 %0, %1" : "=v"(bfr[ni]) : "v"(a_)); } \
  _Pragma("unroll") for (int mi = 0; mi < 8; mi++){ \
    int off = (S) * 32768 + (KHOFF) + (wr * 128 + mi * 16 + lr) * 64 + kg * 16; \
    unsigned a_ = (unsigned)(size_t)(lds3 + SWZ(off)); \
    asm volatile("ds_read_b128 %0, %1" : "=v"(af[mi]) : "v"(a_)); } \
  __builtin_amdgcn_s_setprio(1); \
  LSTEP(7, 0) LSTEP(6, 1) LSTEP(5, 2) LSTEP(4, 3) \
  LSTEP(3, 4) LSTEP(2, 5) LSTEP(1, 6) LSTEP(0, 7) \
  __builtin_amdgcn_s_setprio(0); \
  __builtin_amdgcn_sched_barrier(0); }

__global__ __launch_bounds__(512, 2) void gemm256_fused(
    const float* __restrict__ Ag32,         // 65536 x 1024 f32 (x)
    const unsigned short* __restrict__ Bg,  // 1024 x 1024 bf16 (W_f)
    unsigned short* __restrict__ vt)        // (C, B, T)
{
  extern __shared__ char ldsc[];            // 131072 B
  lds_char* lds3 = (lds_char*)ldsc;
  const int tid = threadIdx.x;
  const int ln  = tid & 63;
  const int wv  = tid >> 6;                 // 8 waves
  const int wr  = wv >> 2;                  // 2 M-waves (128 rows each)
  const int wc  = wv & 3;                   // 4 N-waves (64 cols each)
  const int lr  = ln & 15, kg = ln >> 4;
  const int rowA = wv * 16 + (ln >> 2);
  const int c8   = ln & 3;
  const int id  = blockIdx.x;
  const int jj  = (id & 7) * 128 + (id >> 3);
  const int n0  = (jj & 3) * 256;
  const int m0  = (jj >> 2) * 256;

  f32x4 acc[8][4];
  #pragma unroll
  for (int mi = 0; mi < 8; mi++)
    #pragma unroll
    for (int ni = 0; ni < 4; ni++)
      acc[mi][ni] = (f32x4){0.f, 0.f, 0.f, 0.f};

  float4 areg[2][2][2];

  LOADA(0);
  asm volatile("s_waitcnt vmcnt(0)");
  __builtin_amdgcn_sched_barrier(0);
  CVTWRITE(0);
  __builtin_amdgcn_sched_barrier(0);
  STAGE_B(0, 0); STAGE_B(0, 1);
  __builtin_amdgcn_sched_barrier(0);
  asm volatile("s_waitcnt lgkmcnt(0)");
  __builtin_amdgcn_sched_barrier(0);
  asm volatile("s_waitcnt vmcnt(0)");
  __builtin_amdgcn_sched_barrier(0);
  __builtin_amdgcn_s_barrier();

  short8 af[8], bfr[4];

  #pragma unroll 1
  for (int t = 0; t < 16; ++t){
    const int S = t & 1;

    if (t < 15){
      LOADA(t + 1);
      __builtin_amdgcn_sched_barrier(0);
      STAGE_B(t + 1, 0); STAGE_B(t + 1, 1);
      __builtin_amdgcn_sched_barrier(0);
    }

    KHALF(S, 0)
    KHALF(S, 16384)

    if (t < 15){
      asm volatile("s_waitcnt vmcnt(0)");
      __builtin_amdgcn_sched_barrier(0);
      CVTWRITE(S ^ 1);
      __builtin_amdgcn_sched_barrier(0);
      asm volatile("s_waitcnt lgkmcnt(0)");
      __builtin_amdgcn_sched_barrier(0);
    }
    __builtin_amdgcn_s_barrier();
  }

  #pragma unroll
  for (int mi = 0; mi < 8; mi++)
    #pragma unroll
    for (int ni = 0; ni < 4; ni++){
      int n  = n0 + wc * 64 + ni * 16 + lr;
      int mb = m0 + wr * 128 + mi * 16 + kg * 4;
      int bb = mb >> 9, t = mb & 511;
      ushort4 o;
      o.x = f2bf(acc[mi][ni][0]); o.y = f2bf(acc[mi][ni][1]);
      o.z = f2bf(acc[mi][ni][2]); o.w = f2bf(acc[mi][ni][3]);
      *(ushort4*)&vt[((size_t)n * B_ + bb) * T_ + t] = o;
    }
}

// ---------------- conv via MFMA v4: FULL-CHANNEL blocks (uniform 16 iters, vt read once) ----
// One block per channel: 512 threads = 8 waves = 4 t-tiles x 2 b-halves; each wave owns a
// 128t x 64b output tile. Per iter: 128x32 vt slab reg-staged once (T14), active waves
// (t0w+128 > k0, wave-uniform) do 12 asm ds_reads + <=32 MFMA. Band algebra r2/r14-verified:
// d32 = (t0w-k0)/32 + (mi>>1), row i = ((mi&1)<<4)+lr, per-mi causal skip.
__global__ __launch_bounds__(512) void conv_mfma4(
    const unsigned short* __restrict__ vt,    // (C, B, T) bf16
    const float* __restrict__ pw,             // (C)
    const float* __restrict__ line,           // (T)
    const float* __restrict__ gain,           // (1,1,C)
    unsigned short* __restrict__ Ybf)         // (C, B, T) bf16, gain+relu applied
{
  __shared__ short Bs[128 * 32];              // v slab: 128 b x 32 s (8KB), single buffer
  __shared__ short Ab[16 * 1280];             // all 16 Toeplitz bands (40KB)
  __shared__ unsigned short zbuf[512];        // 1KB
  lds_char* ldsB = (lds_char*)Bs;
  lds_char* ldsA = (lds_char*)Ab;
  const int c   = blockIdx.x;                 // 1024 blocks = 1 channel each (uniform work)
  const int tid = threadIdx.x, lane = tid & 63, wave = tid >> 6;
  const int t0w = (wave >> 1) << 7;           // wave's t-tile: 0,128,256,384
  const int bh  = wave & 1;                   // wave's b-half
  const int lr = lane & 15, kg = lane >> 4;

  // ---- fused band computation (r14-verified indexing), all 16 bands
  {
    float p = pw[c];
    float e = 2.0f + 100.0f / (1.0f + expf(-p));
    for (int k = tid; k < T_; k += 512){
      float lv = line[k];
      float z = (lv > 0.f) ? expf(e * logf(lv)) : 0.f;
      zbuf[k] = f2bf(z);
    }
  }
  __syncthreads();
  for (int idx = tid; idx < 16 * 1280; idx += 512){
    int i = idx / 40, j = idx - i * 40;
    int d32 = i >> 5, ii = i & 31;
    int k = d32 * 32 + ii - j;
    unsigned short v = 0;
    if (j < 32 && k >= 0) v = zbuf[k];
    Ab[idx] = v;
  }
  __syncthreads();                            // Ab visible before any read

  f32x4 acc[8][4];
  #pragma unroll
  for (int mi = 0; mi < 8; mi++)
    #pragma unroll
    for (int ni = 0; ni < 4; ni++)
      acc[mi][ni] = (f32x4){0.f, 0.f, 0.f, 0.f};

  const int r1 = tid >> 2, ch1 = tid & 3;     // 512 threads: 1 row (r1) x 8-short chunk each
  const size_t vbase = (size_t)c * B_ * T_;
  const unsigned adw = (unsigned)(size_t)(ldsB + tid * 16);   // == (r1*32 + ch1*8)*2

  // slab 0 -> regs
  short8 va = *(const short8*)&vt[vbase + (size_t)r1 * T_ + ch1 * 8];

  #pragma unroll 1
  for (int it = 0; it < 16; ++it){
    const int k0 = it << 5;
    // write slab it (regs) -> Bs (compiler auto-waits the va load)
    asm volatile("ds_write_b128 %0, %1" :: "v"(adw), "v"(va));
    asm volatile("s_waitcnt lgkmcnt(0)");
    __builtin_amdgcn_sched_barrier(0);
    __builtin_amdgcn_s_barrier();             // slab visible

    // prefetch slab it+1 -> regs (hides under reads+MFMA+barrier)
    if (it + 1 < 16)
      va = *(const short8*)&vt[vbase + (size_t)r1 * T_ + k0 + 32 + ch1 * 8];

    if (t0w + 128 > k0){                      // wave-uniform causal activity
      short8 bfr[4], afv[8];
      #pragma unroll
      for (int ni = 0; ni < 4; ni++){
        unsigned a_ = (unsigned)(size_t)(ldsB + (bh * 64 + ni * 16 + lr) * 64 + kg * 16);
        asm volatile("ds_read_b128 %0, %1" : "=v"(bfr[ni]) : "v"(a_));
      }
      const int dbase = (t0w - k0) >> 5;      // exact (multiples of 32)
      #pragma unroll
      for (int mi = 0; mi < 8; mi++){
        int d32 = dbase + (mi >> 1);
        int d32c = d32 < 0 ? 0 : d32;
        int i = ((mi & 1) << 4) + lr;
        unsigned a_ = (unsigned)(size_t)(ldsA + (d32c * 1280 + i * 40 + kg * 8) * 2);
        asm volatile("ds_read_b128 %0, %1" : "=v"(afv[mi]) : "v"(a_));
      }
      asm volatile("s_waitcnt lgkmcnt(0)");
      __builtin_amdgcn_sched_barrier(0);
      __builtin_amdgcn_s_setprio(1);
      #pragma unroll
      for (int mi = 0; mi < 8; mi++){
        if (dbase + (mi >> 1) >= 0){          // per-mi causal skip (wave-uniform)
          #pragma unroll
          for (int ni = 0; ni < 4; ni++)
            acc[mi][ni] = __builtin_amdgcn_mfma_f32_16x16x32_bf16(afv[mi], bfr[ni], acc[mi][ni], 0, 0, 0);
        }
      }
      __builtin_amdgcn_s_setprio(0);
      __builtin_amdgcn_sched_barrier(0);
    }
    __builtin_amdgcn_s_barrier();             // reads done before next iter's writes
  }

  const float g = gain[c];
  #pragma unroll
  for (int mi = 0; mi < 8; mi++)
    #pragma unroll
    for (int ni = 0; ni < 4; ni++){
      int t = t0w + mi * 16 + kg * 4;
      int b = bh * 64 + ni * 16 + lr;
      ushort4 o;
      o.x = f2bf(fmaxf(acc[mi][ni][0] * g, 0.f));
      o.y = f2bf(fmaxf(acc[mi][ni][1] * g, 0.f));
      o.z = f2bf(fmaxf(acc[mi][ni][2] * g, 0.f));
      o.w = f2bf(fmaxf(acc[mi][ni][3] * g, 0.f));
      *(ushort4*)&Ybf[((size_t)c * B_ + b) * T_ + t] = o;
    }
}

// ---------------- final: (C,B,T) bf16 -> (B,T,C) f32 ----------------
__global__ __launch_bounds__(256) void final_out(const unsigned short* __restrict__ Ybf,
                                                 float* __restrict__ out){
  __shared__ unsigned short tile[64][72];
  const int c0 = blockIdx.x * 64;
  const int t0 = blockIdx.y * 64;
  const int b  = blockIdx.z;
  const int tid = threadIdx.x;
  const int cr = tid >> 4;
  const int t4 = (tid & 15) * 4;
  for (int q = 0; q < 64; q += 16){
    ushort4 u = *(const ushort4*)&Ybf[((size_t)(c0 + cr + q) * B_ + b) * T_ + t0 + t4];
    *(ushort4*)&tile[cr + q][t4] = u;
  }
  __syncthreads();
  const int tr = tid >> 4;
  const int c4 = (tid & 15) * 4;
  for (int q = 0; q < 64; q += 16){
    int t = tr + q;
    float4 o;
    o.x = __uint_as_float((unsigned)tile[c4 + 0][t] << 16);
    o.y = __uint_as_float((unsigned)tile[c4 + 1][t] << 16);
    o.z = __uint_as_float((unsigned)tile[c4 + 2][t] << 16);
    o.w = __uint_as_float((unsigned)tile[c4 + 3][t] << 16);
    *(float4*)&out[((size_t)b * T_ + t0 + t) * C_ + c0 + c4] = o;
  }
}

extern "C" void kernel_launch(void* const* d_in, const int* in_sizes, int n_in,
                              void* d_out, int out_size, void* d_ws, size_t ws_size,
                              hipStream_t stream)
{
  (void)in_sizes; (void)n_in; (void)out_size; (void)ws_size;
  const float* x    = (const float*)d_in[0];
  const float* Wp   = (const float*)d_in[1];
  const float* Wv   = (const float*)d_in[2];
  const float* gain = (const float*)d_in[3];
  const float* pw   = (const float*)d_in[4];
  const float* line = (const float*)d_in[5];
  float* out = (float*)d_out;

  // ws: [Ybf 128MB][WpT 2MB][Wv_bf 2MB][W_f 2MB]
  char* ws = (char*)d_ws;
  unsigned short* Ybf   = (unsigned short*)ws;
  unsigned short* WpT   = (unsigned short*)(ws + 134217728);
  unsigned short* Wv_bf = (unsigned short*)(ws + 134217728 + 2097152);
  unsigned short* W_f   = (unsigned short*)(ws + 134217728 + 2 * 2097152);
  // d_out (256MB f32) reused as scratch:
  unsigned short* vt    = (unsigned short*)d_out + 67108864;         // upper 128MB (dead after conv)

  // weights
  cast_f32_bf16<<<256, 256, 0, stream>>>(Wv, Wv_bf, (long)C_ * C_);
  transpose_cast<<<dim3(32, 32), dim3(32, 8), 0, stream>>>(Wp, WpT);
  gemm_bt_bf16<<<dim3(8, 8), 256, 0, stream>>>(Wv_bf, WpT, W_f, C_, C_, C_);
  // v = x @ W_f^T with fused f32->bf16 A-staging + lgkm ladder (r15-exact)
  gemm256_fused<<<1024, 512, 131072, stream>>>(x, W_f, vt);
  // conv + gain + relu -> Ybf (C,B,T); full-channel blocks, reg-staged vt, in-kernel bands
  conv_mfma4<<<1024, 512, 0, stream>>>(vt, pw, line, gain, Ybf);
  // transpose to (B,T,C) f32
  final_out<<<dim3(16, 8, 128), 256, 0, stream>>>(Ybf, out);
}